// Round 17
// baseline (261.922 us; speedup 1.0000x reference)
//
#include <hip/hip_runtime.h>
#include <hip/hip_bf16.h>
#include <stdint.h>

// ---------------------------------------------------------------------------
// Fused attention block, bf16 MFMA pipeline:
//   prep (fused rope-table + cvt(x) + transpose w_qkv/w_out) ->
//   GEMM qkv (gemm8p BK=64, 64x64/wave, single-barrier K-loop; epilogue
//   fuses bias+RMSNorm+RoPE for q,k into qk[4096][4096] and writes V
//   DIRECTLY TRANSPOSED into vt[bh][d][t]) ->
//   flash attention (R10 structure + double-buffered K/V, stage-at-top,
//   ONE barrier/tile) -> GEMM out-proj (+bias, fp32)
// ---------------------------------------------------------------------------

typedef unsigned short ushort8 __attribute__((ext_vector_type(8)));
typedef unsigned short ushort4v __attribute__((ext_vector_type(4)));
typedef short          bf16x8 __attribute__((ext_vector_type(8)));
typedef float          f32x4  __attribute__((ext_vector_type(4)));

#define B_   2
#define L_   2048
#define DM   2048
#define NH   16
#define HD   128
#define QKW  4096   // q,k packed row width

__device__ __forceinline__ uint16_t f2bf(float f){
  uint32_t u = __builtin_bit_cast(uint32_t, f);
  u += 0x7FFFu + ((u >> 16) & 1u);          // RNE
  return (uint16_t)(u >> 16);
}
__device__ __forceinline__ float bf2f(uint16_t h){
  uint32_t u = ((uint32_t)h) << 16;
  return __builtin_bit_cast(float, u);
}

// async global->LDS, 16B per lane; LDS dest is wave-uniform base + lane*16
#define GLD16(gp, lp) __builtin_amdgcn_global_load_lds( \
  (const __attribute__((address_space(1))) void*)(gp),  \
  (__attribute__((address_space(3))) void*)(lp), 16, 0, 0)

// ---------------- fused prep: transposes + cvt + rope table --------------
// blocks [0,3072): transpose w_qkv; [3072,4096): transpose w_out;
// [4096,8192): cvt x; [8192,8704): rope table
__global__ __launch_bounds__(256) void prep(
    const float* __restrict__ Wqkv, uint16_t* __restrict__ WqkvT,
    const float* __restrict__ Wout, uint16_t* __restrict__ WoutT,
    const float* __restrict__ x, uint16_t* __restrict__ xb,
    float* __restrict__ ct, float* __restrict__ st)
{
  __shared__ float T[64][65];
  const int bid = blockIdx.x;
  const int tid = threadIdx.x;

  if (bid < 4096){
    const float* W; uint16_t* Wt; int R = 2048, C; int rb, cb;
    if (bid < 3072){ W = Wqkv; Wt = WqkvT; C = 6144; rb = bid & 31; cb = bid >> 5; }
    else           { int i = bid - 3072; W = Wout; Wt = WoutT; C = 2048; rb = i & 31; cb = i >> 5; }
#pragma unroll
    for (int i=0;i<4;i++){
      int rr = i*16 + (tid >> 4);
      int cc = (tid & 15) * 4;
      float4 v = *(const float4*)(W + (size_t)(rb*64 + rr) * C + cb*64 + cc);
      T[rr][cc] = v.x; T[rr][cc+1] = v.y; T[rr][cc+2] = v.z; T[rr][cc+3] = v.w;
    }
    __syncthreads();
    const int oc = tid >> 2, rc = (tid & 3) * 16;
    ushort8 o0, o1;
#pragma unroll
    for (int j=0;j<8;j++){ o0[j] = f2bf(T[rc+j][oc]); o1[j] = f2bf(T[rc+8+j][oc]); }
    size_t ob = (size_t)(cb*64 + oc) * R + rb*64 + rc;
    *(ushort8*)(Wt + ob)     = o0;
    *(ushort8*)(Wt + ob + 8) = o1;
  } else if (bid < 8192){
    int i = (bid - 4096) * 256 + tid;        // 1048576 x 8 elements
    const float4* xv = (const float4*)x;
    float4 a = xv[(size_t)i*2], b = xv[(size_t)i*2+1];
    ushort8 v;
    v[0]=f2bf(a.x); v[1]=f2bf(a.y); v[2]=f2bf(a.z); v[3]=f2bf(a.w);
    v[4]=f2bf(b.x); v[5]=f2bf(b.y); v[6]=f2bf(b.z); v[7]=f2bf(b.w);
    *(ushort8*)(xb + (size_t)i*8) = v;
  } else {
    int i = (bid - 8192) * 256 + tid;        // 131072 table entries
    int t = i >> 6, d = i & 63;
    float invf = powf(10000.f, -(float)d * (1.f/64.f));
    float s, c;
    sincosf((float)t * invf, &s, &c);
    ct[i] = c; st[i] = s;
  }
}

// ---------------- GEMM: C = A[M][K] * Bt[N][K]^T + bias ------------------
// Single-barrier K-loop (R10, ~905 TF): 3-slot LDS ring, prefetch-2,
// counted vmcnt(6), T2 XOR-swizzle (0 conflicts), T5 setprio, 8 waves as
// 4M x 2N (64x64/wave, acc[4][4]).
// MODE 1 (QKV): q/k -> fused bias+RMSNorm+RoPE into qk[ldc=4096];
//   v -> bias + direct transposed store into vt[bh][d][t] (Cv2).
// MODE 0 (out-proj): fp32 bias store, row stride ldc.
template<int MODE>
__global__ __launch_bounds__(512, 2) void gemm8p(
    const uint16_t* __restrict__ A, const uint16_t* __restrict__ Bt,
    const float* __restrict__ bias, void* __restrict__ Cv, void* __restrict__ Cv2,
    int M, int N, int K, int nbn, int ldc,
    const float* __restrict__ qs, const float* __restrict__ ks,
    const float* __restrict__ ct, const float* __restrict__ st)
{
  __shared__ uint16_t LA[3*16384];   // 3 x [256][64]
  __shared__ uint16_t LB[3*8192];    // 3 x [128][64]
  __shared__ float sums[4][2][64];   // rms half-sum exchange (2 KB)
  const int nwg = (M >> 8) * nbn;
  const int q8  = nwg >> 3;
  const int id  = ((int)blockIdx.x & 7) * q8 + ((int)blockIdx.x >> 3);
  const int bm = id / nbn, bn = id % nbn;
  const int tid = threadIdx.x;
  const int lane = tid & 63, w = tid >> 6;
  const int wm = w & 3, wn = w >> 2;          // 4M x 2N, 64x64 per wave
  const int l15 = lane & 15, lh = lane >> 4;
  const int NT = K >> 6;

  // staging: per-lane inverse-swizzled global source column
  const int qs3 = ((lane & 7) ^ ((lane >> 3) & 7)) * 8;
  const uint16_t* gA_ = A  + (size_t)((bm << 8) + (w << 5) + (lane >> 3)) * K + qs3;
  const uint16_t* gB_ = Bt + (size_t)((bn << 7) + (w << 4) + (lane >> 3)) * K + qs3;
  uint16_t* lA_ = LA + (w << 11);    // wave-uniform LDS bases
  uint16_t* lB_ = LB + (w << 10);

  // fragment-read swizzled offsets (elements)
  const int sw0 = ((lh       ^ (l15 & 7)) << 3);   // kc=0
  const int sw1 = (((4 | lh) ^ (l15 & 7)) << 3);   // kc=1
  const int aoff = (((wm << 6) + l15) << 6);       // rows wm*64 + mi*16 + l15
  const int boff = (((wn << 5) + l15) << 6);       // rows wn*32 + ... + l15
  const int bno[4] = {0, 1024, 4096, 5120};        // (ni&1)*16*64 + (ni>>1)*64*64

  f32x4 acc[4][4];
#pragma unroll
  for (int i=0;i<4;i++)
#pragma unroll
    for (int j=0;j<4;j++) acc[i][j] = f32x4{0.f,0.f,0.f,0.f};

  auto STAGE_A = [&](int tt, int s, int i){
    GLD16(gA_ + (size_t)tt*64 + (size_t)(i*8)*K, lA_ + s*16384 + i*512);
  };
  auto STAGE_B = [&](int tt, int s, int i){
    GLD16(gB_ + (size_t)tt*64 + (size_t)(i*8)*K, lB_ + s*8192 + i*512);
  };

  // prologue: stage tiles 0,1; wait tile 0 (6 of 12 outstanding = tile 1)
#pragma unroll
  for (int i=0;i<4;i++) STAGE_A(0, 0, i);
#pragma unroll
  for (int i=0;i<2;i++) STAGE_B(0, 0, i);
#pragma unroll
  for (int i=0;i<4;i++) STAGE_A(1, 1, i);
#pragma unroll
  for (int i=0;i<2;i++) STAGE_B(1, 1, i);
  asm volatile("s_waitcnt vmcnt(6)" ::: "memory");
  __builtin_amdgcn_s_barrier();

  int sl = 0, sl2 = 2;
  for (int t = 0; t < NT; ++t){
    const bool pf = (t + 2 < NT);
    const uint16_t* la = LA + sl*16384;
    const uint16_t* lb = LB + sl*8192;

    // all fragment reads for this tile (both kc) - async, lgkm-counted
    bf16x8 af0[4], bf0[4], af1[4], bf1[4];
#pragma unroll
    for (int mi=0;mi<4;mi++) af0[mi] = *(const bf16x8*)(la + aoff + mi*1024 + sw0);
#pragma unroll
    for (int ni=0;ni<4;ni++) bf0[ni] = *(const bf16x8*)(lb + boff + bno[ni] + sw0);
#pragma unroll
    for (int mi=0;mi<4;mi++) af1[mi] = *(const bf16x8*)(la + aoff + mi*1024 + sw1);
#pragma unroll
    for (int ni=0;ni<4;ni++) bf1[ni] = *(const bf16x8*)(lb + boff + bno[ni] + sw1);
    // next-next tile staging (slot disjoint from all live readers)
    if (pf){
      STAGE_A(t+2, sl2, 0); STAGE_A(t+2, sl2, 1);
      STAGE_A(t+2, sl2, 2); STAGE_A(t+2, sl2, 3);
      STAGE_B(t+2, sl2, 0); STAGE_B(t+2, sl2, 1);
    }
    // 32 MFMAs; compiler inserts fine-grained lgkmcnt before first uses
    __builtin_amdgcn_s_setprio(1);
#pragma unroll
    for (int mi=0;mi<4;mi++)
#pragma unroll
      for (int ni=0;ni<4;ni++)
        acc[mi][ni] = __builtin_amdgcn_mfma_f32_16x16x32_bf16(af0[mi], bf0[ni], acc[mi][ni], 0, 0, 0);
#pragma unroll
    for (int mi=0;mi<4;mi++)
#pragma unroll
      for (int ni=0;ni<4;ni++)
        acc[mi][ni] = __builtin_amdgcn_mfma_f32_16x16x32_bf16(af1[mi], bf1[ni], acc[mi][ni], 0, 0, 0);
    __builtin_amdgcn_s_setprio(0);

    // ---- tile boundary: counted vmcnt + single barrier ----
    if (t < NT-2)       { asm volatile("s_waitcnt vmcnt(6)" ::: "memory"); }
    else if (t == NT-2) { asm volatile("s_waitcnt vmcnt(0)" ::: "memory"); }
    if (t < NT-1) __builtin_amdgcn_s_barrier();
    sl  = (sl  == 2) ? 0 : sl  + 1;
    sl2 = (sl2 == 2) ? 0 : sl2 + 1;
  }

  // ---- epilogue ----
  const int cm = (bm << 8) + (wm << 6);
  const int cn = (bn << 7);
  int dc[4];
#pragma unroll
  for (int ni=0;ni<4;ni++) dc[ni] = (wn<<5) + ((ni>>1)<<6) + ((ni&1)<<4) + l15;
  float bs[4];
#pragma unroll
  for (int ni=0;ni<4;ni++) bs[ni] = bias[cn + dc[ni]];

  if (MODE == 0){
#pragma unroll
    for (int mi=0;mi<4;mi++)
#pragma unroll
      for (int r=0;r<4;r++){
        int rowg = cm + mi*16 + lh*4 + r;       // C/D: col=lane&15, row=(lane>>4)*4+r
#pragma unroll
        for (int ni=0;ni<4;ni++)
          ((float*)Cv)[(size_t)rowg * ldc + cn + dc[ni]] = acc[mi][ni][r] + bs[ni];
      }
  } else {
    const int part = bn >> 4;                   // 0=q, 1=k, 2=v
    if (part == 2){
      // bias + direct transposed store: vt[((b*16+h)*128 + d)*2048 + t]
      uint16_t* vtp = (uint16_t*)Cv2;
      const int h  = bn & 15;
      const int bb = cm >> 11;                  // batch index (256-row blocks don't cross)
      const int t0 = (cm & (L_-1)) + lh*4;
#pragma unroll
      for (int mi=0;mi<4;mi++){
#pragma unroll
        for (int ni=0;ni<4;ni++){
          ushort4v pk;
#pragma unroll
          for (int r=0;r<4;r++) pk[r] = f2bf(acc[mi][ni][r] + bs[ni]);
          *(ushort4v*)(vtp + ((size_t)((bb*16 + h)*128 + dc[ni]))*L_ + t0 + mi*16) = pk;
        }
      }
    } else {
      // fused bias + RMSNorm + RoPE (fp32 domain) -> qk[ldc=4096]
      uint16_t* Cb = (uint16_t*)Cv;
      const float* scp = part ? ks : qs;
      float scv[4];
#pragma unroll
      for (int ni=0;ni<4;ni++) scv[ni] = scp[dc[ni]];
      float ssum[4][4];
#pragma unroll
      for (int mi=0;mi<4;mi++)
#pragma unroll
        for (int r=0;r<4;r++){
          float s = 0.f;
#pragma unroll
          for (int ni=0;ni<4;ni++){
            float v = acc[mi][ni][r] + bs[ni];
            acc[mi][ni][r] = v;
            s += v*v;
          }
          s += __shfl_xor(s, 1); s += __shfl_xor(s, 2);
          s += __shfl_xor(s, 4); s += __shfl_xor(s, 8);
          ssum[mi][r] = s;                       // own 64-col half sum
        }
      if (l15 == 0){
#pragma unroll
        for (int mi=0;mi<4;mi++)
#pragma unroll
          for (int r=0;r<4;r++) sums[wm][wn][mi*16 + lh*4 + r] = ssum[mi][r];
      }
      __syncthreads();
      const int dd0 = (wn<<5) + l15, dd1 = dd0 + 16;
#pragma unroll
      for (int mi=0;mi<4;mi++){
#pragma unroll
        for (int r=0;r<4;r++){
          int rid = mi*16 + lh*4 + r;
          float tot = ssum[mi][r] + sums[wm][wn^1][rid];
          float iv = rsqrtf(tot * 0.0078125f + 1e-6f);
          int rowg = cm + rid;
          int t = rowg & (L_-1);
          float y0 = acc[mi][0][r] * iv * scv[0];
          float y1 = acc[mi][1][r] * iv * scv[1];
          float y2 = acc[mi][2][r] * iv * scv[2];
          float y3 = acc[mi][3][r] * iv * scv[3];
          float c0 = ct[t*64 + dd0], s0 = st[t*64 + dd0];
          float c1 = ct[t*64 + dd1], s1 = st[t*64 + dd1];
          size_t rb_ = (size_t)rowg * ldc + cn;
          Cb[rb_ + dc[0]] = f2bf(y0*c0 - y2*s0);
          Cb[rb_ + dc[1]] = f2bf(y1*c1 - y3*s1);
          Cb[rb_ + dc[2]] = f2bf(y0*s0 + y2*c0);
          Cb[rb_ + dc[3]] = f2bf(y1*s1 + y3*c1);
        }
      }
    }
  }
}

// ---------------- flash attention (causal, balanced pairs) ---------------
// grid (qp=16, bh=32); block handles q-tiles {qp, 31-qp}: 33 K-tile iters,
// uniform; 512 blocks = 2/CU (81 KB LDS x2 = 158 KB <= 160 KB).
// KVBLK=64, 4 waves x 16 q-rows, Q in regs. THIS ROUND: double-buffered K/V
// with STAGE-AT-TOP ordering -> ONE barrier per tile. Stage writes for tile
// kt+1 issue before QK^T, so the lgkmcnt(0) before PV has the whole
// QK^T+softmax span to cover them (R13's failure was stage-after-QK^T).
// Swapped QK^T (mfma(K,Q)) lane-local softmax; T5 setprio; T13 defer-max.
__global__ __launch_bounds__(256) void flash_attn(
    const uint16_t* __restrict__ qk, const uint16_t* __restrict__ vt,
    uint16_t* __restrict__ ao)
{
  const int qp = blockIdx.x;
  const int bh = blockIdx.y;
  const int b = bh >> 4, h = bh & 15;
  const int tid = threadIdx.x;
  const int lane = tid & 63, w = tid >> 6;
  const int l15 = lane & 15, lh = lane >> 4;

  __shared__ uint16_t Ks[2][64][136];
  __shared__ uint16_t Vs[2][128][72];
  __shared__ uint16_t Ps[4][16][72];

  const float SCL = 0.12751744f;      // (1/sqrt(128)) * log2(e)

  for (int sel = 0; sel < 2; sel++){
    const int qb = sel ? (31 - qp) : qp;

    const size_t qrow = (size_t)b * L_ + qb*64 + w*16 + l15;
    const uint16_t* qp_ = qk + qrow * QKW + h * HD;
    bf16x8 qf[4];
#pragma unroll
    for (int c = 0; c < 4; c++) qf[c] = *(const bf16x8*)(qp_ + c*32 + lh*8);

    float m_s = -3.0e38f, l_s = 0.f;   // per-lane scalars for q = l15
    f32x4 oacc[8];
#pragma unroll
    for (int nt = 0; nt < 8; nt++) oacc[nt] = f32x4{0.f,0.f,0.f,0.f};

    const int ntile = qb + 1;
    ushort8 rk[4], rv[4];

    // ---- prologue: protect buffers from prior-sel readers; fill buf0 ----
    __syncthreads();
#pragma unroll
    for (int i = 0; i < 4; i++){
      int g = i*256 + tid, row = g >> 4, c = g & 15;
      rk[i] = *(const ushort8*)(qk + ((size_t)b*L_ + row)*QKW + DM + h*HD + c*8);
    }
#pragma unroll
    for (int i = 0; i < 4; i++){
      int g = i*256 + tid, d = g >> 3, c = g & 7;
      rv[i] = *(const ushort8*)(vt + ((size_t)bh*HD + d)*L_ + c*8);
    }
#pragma unroll
    for (int i = 0; i < 4; i++){ int g = i*256+tid; *(ushort8*)(&Ks[0][g>>4][(g&15)*8]) = rk[i]; }
#pragma unroll
    for (int i = 0; i < 4; i++){ int g = i*256+tid; *(ushort8*)(&Vs[0][g>>3][(g&7)*8]) = rv[i]; }
    if (ntile > 1){                    // tile 1 -> regs
#pragma unroll
      for (int i = 0; i < 4; i++){
        int g = i*256 + tid, row = g >> 4, c = g & 15;
        rk[i] = *(const ushort8*)(qk + ((size_t)b*L_ + 64 + row)*QKW + DM + h*HD + c*8);
      }
#pragma unroll
      for (int i = 0; i < 4; i++){
        int g = i*256 + tid, d = g >> 3, c = g & 7;
        rv[i] = *(const ushort8*)(vt + ((size_t)bh*HD + d)*L_ + 64 + c*8);
      }
    }
    __syncthreads();

    for (int kt = 0; kt < ntile; kt++){
      const int c = kt & 1;

      // ---- stage tile kt+1 -> buf[c^1] FIRST (readers were tile kt-1,
      //      separated by its end barrier; lgkmcnt(0) below is far away) ----
      if (kt + 1 < ntile){
#pragma unroll
        for (int i = 0; i < 4; i++){ int g = i*256+tid; *(ushort8*)(&Ks[c^1][g>>4][(g&15)*8]) = rk[i]; }
#pragma unroll
        for (int i = 0; i < 4; i++){ int g = i*256+tid; *(ushort8*)(&Vs[c^1][g>>3][(g&7)*8]) = rv[i]; }
      }
      // ---- prefetch tile kt+2 -> regs (reg-dep orders after ds_writes) ----
      if (kt + 2 < ntile){
        const int k2 = (kt + 2) * 64;
#pragma unroll
        for (int i = 0; i < 4; i++){
          int g = i*256 + tid, row = g >> 4, cc = g & 15;
          rk[i] = *(const ushort8*)(qk + ((size_t)b*L_ + k2 + row)*QKW + DM + h*HD + cc*8);
        }
#pragma unroll
        for (int i = 0; i < 4; i++){
          int g = i*256 + tid, d = g >> 3, cc = g & 7;
          rv[i] = *(const ushort8*)(vt + ((size_t)bh*HD + d)*L_ + k2 + cc*8);
        }
      }

      // ---- S^T = K Q^T : s[nt][r] = S[k = nt*16+lh*4+r][q = l15] ----
      f32x4 s[4];
#pragma unroll
      for (int nt = 0; nt < 4; nt++) s[nt] = f32x4{0.f,0.f,0.f,0.f};
      __builtin_amdgcn_s_setprio(1);
#pragma unroll
      for (int cc = 0; cc < 4; cc++){
#pragma unroll
        for (int nt = 0; nt < 4; nt++){
          bf16x8 kf = *(const bf16x8*)(&Ks[c][nt*16 + l15][cc*32 + lh*8]);
          s[nt] = __builtin_amdgcn_mfma_f32_16x16x32_bf16(kf, qf[cc], s[nt], 0, 0, 0);
        }
      }
      __builtin_amdgcn_s_setprio(0);

      // ---- scale + causal mask (log2 domain) ----
      const bool diag = (kt == qb);
      const int qg = w*16 + l15;            // q within block
      const int kb = lh*4;                  // k base within each 16-k tile
#pragma unroll
      for (int nt = 0; nt < 4; nt++){
#pragma unroll
        for (int r = 0; r < 4; r++){
          float v = s[nt][r] * SCL;
          if (diag && (nt*16 + kb + r > qg)) v = -1.0e30f;
          s[nt][r] = v;
        }
      }
      // ---- lane-local max over 16 k + 2 cross-lh shuffles ----
      float pm = s[0][0];
#pragma unroll
      for (int nt = 0; nt < 4; nt++)
#pragma unroll
        for (int r = 0; r < 4; r++) pm = fmaxf(pm, s[nt][r]);
      pm = fmaxf(pm, __shfl_xor(pm, 16));
      pm = fmaxf(pm, __shfl_xor(pm, 32));
      // ---- T13 defer-max ----
      if (!__all(pm - m_s <= 8.0f)){
        float mn = fmaxf(m_s, pm);
        float alpha = exp2f(m_s - mn);
        m_s = mn; l_s *= alpha;
        float ar[4];
#pragma unroll
        for (int r = 0; r < 4; r++) ar[r] = __shfl(alpha, lh*4 + r);
#pragma unroll
        for (int nt = 0; nt < 8; nt++)
#pragma unroll
          for (int r = 0; r < 4; r++) oacc[nt][r] *= ar[r];
      }
      // ---- P = exp2(S - m), pack 4 consecutive k, store b64; sum ----
      float rs = 0.f;
#pragma unroll
      for (int nt = 0; nt < 4; nt++){
        float p0 = exp2f(s[nt][0] - m_s);
        float p1 = exp2f(s[nt][1] - m_s);
        float p2 = exp2f(s[nt][2] - m_s);
        float p3 = exp2f(s[nt][3] - m_s);
        rs += (p0 + p1) + (p2 + p3);
        uint2 pk;
        pk.x = (uint32_t)f2bf(p0) | ((uint32_t)f2bf(p1) << 16);
        pk.y = (uint32_t)f2bf(p2) | ((uint32_t)f2bf(p3) << 16);
        *(uint2*)(&Ps[w][l15][nt*16 + kb]) = pk;
      }
      rs += __shfl_xor(rs, 16);
      rs += __shfl_xor(rs, 32);
      l_s += rs;

      asm volatile("s_waitcnt lgkmcnt(0)" ::: "memory");   // Ps + (long-done) staging writes
      // ---- O += P V : A=P[16q][64k] (LDS), B=V[64k][128d] (LDS) ----
      __builtin_amdgcn_s_setprio(1);
#pragma unroll
      for (int kc = 0; kc < 2; kc++){
        bf16x8 pf = *(const bf16x8*)(&Ps[w][l15][kc*32 + lh*8]);
#pragma unroll
        for (int nt = 0; nt < 8; nt++){
          bf16x8 vf = *(const bf16x8*)(&Vs[c][nt*16 + l15][kc*32 + lh*8]);
          oacc[nt] = __builtin_amdgcn_mfma_f32_16x16x32_bf16(pf, vf, oacc[nt], 0, 0, 0);
        }
      }
      __builtin_amdgcn_s_setprio(0);

      // ---- single tile-boundary barrier: buf[c^1] visible; buf[c] reads
      //      drained (lgkm at barrier) before tile kt+1 overwrites it ----
      if (kt + 1 < ntile) __syncthreads();
    }
    // ---- epilogue: redistribute l to oacc rows, O /= l, write ----
    float invl[4];
#pragma unroll
    for (int r = 0; r < 4; r++) invl[r] = 1.f / __shfl(l_s, lh*4 + r);
#pragma unroll
    for (int nt = 0; nt < 8; nt++){
#pragma unroll
      for (int r = 0; r < 4; r++){
        float v = oacc[nt][r] * invl[r];
        size_t row = (size_t)b*L_ + qb*64 + w*16 + lh*4 + r;
        ao[row * DM + h*HD + nt*16 + l15] = f2bf(v);
      }
    }
  }
}

// ---------------------------------------------------------------------------
extern "C" void kernel_launch(void* const* d_in, const int* in_sizes, int n_in,
                              void* d_out, int out_size, void* d_ws, size_t ws_size,
                              hipStream_t stream)
{
  (void)in_sizes; (void)n_in; (void)out_size; (void)ws_size;
  const float* x       = (const float*)d_in[0];
  const float* w_qkv   = (const float*)d_in[1];
  const float* b_qkv   = (const float*)d_in[2];
  const float* q_scale = (const float*)d_in[3];
  const float* k_scale = (const float*)d_in[4];
  const float* w_out   = (const float*)d_in[5];
  const float* b_out   = (const float*)d_in[6];
  float* out = (float*)d_out;

  // workspace layout (101.7 MB), lifetime-based reuse
  char* ws = (char*)d_ws;
  uint16_t* qk    = (uint16_t*)(ws);                  // 33,554,432 B  [4096][4096]
  uint16_t* vt    = (uint16_t*)(ws + 33554432);       // 16,777,216 B  [32][128][2048]
  uint16_t* reg1  = (uint16_t*)(ws + 50331648);       // 16,777,216 B  xb -> ao
  uint16_t* wqkvT = (uint16_t*)(ws + 67108864);       // 25,165,824 B
  uint16_t* woutT = (uint16_t*)(ws + 92274688);       //  8,388,608 B
  float*    ct    = (float*)(ws + 100663296);         //    524,288 B
  float*    st    = ct + 131072;                      //    524,288 B

  uint16_t* xb = reg1;   // x bf16 [4096][2048]  (dead after gemm_qkv)
  uint16_t* ao = reg1;   // attn out bf16 [4096][2048]

  prep        <<<8704, 256, 0, stream>>>(w_qkv, wqkvT, w_out, woutT, x, xb, ct, st);
  gemm8p<1>   <<<768, 512, 0, stream>>>(xb, wqkvT, b_qkv, qk, vt,
                                        4096, 6144, 2048, 48, 4096,
                                        q_scale, k_scale, ct, st);
  flash_attn  <<<dim3(16, 32), 256, 0, stream>>>(qk, vt, ao);
  gemm8p<0>   <<<256, 512, 0, stream>>>(ao, woutT, b_out, out, nullptr,
                                        4096, 2048, 2048, 16, 2048,
                                        nullptr, nullptr, nullptr, nullptr);
}

// Round 18
// 247.552 us; speedup vs baseline: 1.0580x; 1.0580x over previous
//
#include <hip/hip_runtime.h>
#include <hip/hip_bf16.h>
#include <stdint.h>

// ---------------------------------------------------------------------------
// Fused attention block, bf16 MFMA pipeline:
//   prep (fused rope-table + cvt(x) + transpose w_qkv/w_out) ->
//   GEMM qkv (gemm8p BK=64, 64x64/wave, single-barrier K-loop; epilogue
//   fuses bias+RMSNorm+RoPE for q,k into qk[4096][4096] and writes V
//   DIRECTLY TRANSPOSED into vt[bh][d][t]) ->
//   flash attention (R16 structure, XCD-local grid: all qp-blocks of one
//   bh on one XCD -> K/V L2-resident) -> GEMM out-proj (+bias, fp32)
// ---------------------------------------------------------------------------

typedef unsigned short ushort8 __attribute__((ext_vector_type(8)));
typedef unsigned short ushort4v __attribute__((ext_vector_type(4)));
typedef short          bf16x8 __attribute__((ext_vector_type(8)));
typedef float          f32x4  __attribute__((ext_vector_type(4)));

#define B_   2
#define L_   2048
#define DM   2048
#define NH   16
#define HD   128
#define QKW  4096   // q,k packed row width

__device__ __forceinline__ uint16_t f2bf(float f){
  uint32_t u = __builtin_bit_cast(uint32_t, f);
  u += 0x7FFFu + ((u >> 16) & 1u);          // RNE
  return (uint16_t)(u >> 16);
}
__device__ __forceinline__ float bf2f(uint16_t h){
  uint32_t u = ((uint32_t)h) << 16;
  return __builtin_bit_cast(float, u);
}

// async global->LDS, 16B per lane; LDS dest is wave-uniform base + lane*16
#define GLD16(gp, lp) __builtin_amdgcn_global_load_lds( \
  (const __attribute__((address_space(1))) void*)(gp),  \
  (__attribute__((address_space(3))) void*)(lp), 16, 0, 0)

// ---------------- fused prep: transposes + cvt + rope table --------------
// blocks [0,3072): transpose w_qkv; [3072,4096): transpose w_out;
// [4096,8192): cvt x; [8192,8704): rope table
__global__ __launch_bounds__(256) void prep(
    const float* __restrict__ Wqkv, uint16_t* __restrict__ WqkvT,
    const float* __restrict__ Wout, uint16_t* __restrict__ WoutT,
    const float* __restrict__ x, uint16_t* __restrict__ xb,
    float* __restrict__ ct, float* __restrict__ st)
{
  __shared__ float T[64][65];
  const int bid = blockIdx.x;
  const int tid = threadIdx.x;

  if (bid < 4096){
    const float* W; uint16_t* Wt; int R = 2048, C; int rb, cb;
    if (bid < 3072){ W = Wqkv; Wt = WqkvT; C = 6144; rb = bid & 31; cb = bid >> 5; }
    else           { int i = bid - 3072; W = Wout; Wt = WoutT; C = 2048; rb = i & 31; cb = i >> 5; }
#pragma unroll
    for (int i=0;i<4;i++){
      int rr = i*16 + (tid >> 4);
      int cc = (tid & 15) * 4;
      float4 v = *(const float4*)(W + (size_t)(rb*64 + rr) * C + cb*64 + cc);
      T[rr][cc] = v.x; T[rr][cc+1] = v.y; T[rr][cc+2] = v.z; T[rr][cc+3] = v.w;
    }
    __syncthreads();
    const int oc = tid >> 2, rc = (tid & 3) * 16;
    ushort8 o0, o1;
#pragma unroll
    for (int j=0;j<8;j++){ o0[j] = f2bf(T[rc+j][oc]); o1[j] = f2bf(T[rc+8+j][oc]); }
    size_t ob = (size_t)(cb*64 + oc) * R + rb*64 + rc;
    *(ushort8*)(Wt + ob)     = o0;
    *(ushort8*)(Wt + ob + 8) = o1;
  } else if (bid < 8192){
    int i = (bid - 4096) * 256 + tid;        // 1048576 x 8 elements
    const float4* xv = (const float4*)x;
    float4 a = xv[(size_t)i*2], b = xv[(size_t)i*2+1];
    ushort8 v;
    v[0]=f2bf(a.x); v[1]=f2bf(a.y); v[2]=f2bf(a.z); v[3]=f2bf(a.w);
    v[4]=f2bf(b.x); v[5]=f2bf(b.y); v[6]=f2bf(b.z); v[7]=f2bf(b.w);
    *(ushort8*)(xb + (size_t)i*8) = v;
  } else {
    int i = (bid - 8192) * 256 + tid;        // 131072 table entries
    int t = i >> 6, d = i & 63;
    float invf = powf(10000.f, -(float)d * (1.f/64.f));
    float s, c;
    sincosf((float)t * invf, &s, &c);
    ct[i] = c; st[i] = s;
  }
}

// ---------------- GEMM: C = A[M][K] * Bt[N][K]^T + bias ------------------
// Single-barrier K-loop (R10, ~905 TF): 3-slot LDS ring, prefetch-2,
// counted vmcnt(6), T2 XOR-swizzle (0 conflicts), T5 setprio, 8 waves as
// 4M x 2N (64x64/wave, acc[4][4]).
// MODE 1 (QKV): q/k -> fused bias+RMSNorm+RoPE into qk[ldc=4096];
//   v -> bias + direct transposed store into vt[bh][d][t] (Cv2).
// MODE 0 (out-proj): fp32 bias store, row stride ldc.
template<int MODE>
__global__ __launch_bounds__(512, 2) void gemm8p(
    const uint16_t* __restrict__ A, const uint16_t* __restrict__ Bt,
    const float* __restrict__ bias, void* __restrict__ Cv, void* __restrict__ Cv2,
    int M, int N, int K, int nbn, int ldc,
    const float* __restrict__ qs, const float* __restrict__ ks,
    const float* __restrict__ ct, const float* __restrict__ st)
{
  __shared__ uint16_t LA[3*16384];   // 3 x [256][64]
  __shared__ uint16_t LB[3*8192];    // 3 x [128][64]
  __shared__ float sums[4][2][64];   // rms half-sum exchange (2 KB)
  const int nwg = (M >> 8) * nbn;
  const int q8  = nwg >> 3;
  const int id  = ((int)blockIdx.x & 7) * q8 + ((int)blockIdx.x >> 3);
  const int bm = id / nbn, bn = id % nbn;
  const int tid = threadIdx.x;
  const int lane = tid & 63, w = tid >> 6;
  const int wm = w & 3, wn = w >> 2;          // 4M x 2N, 64x64 per wave
  const int l15 = lane & 15, lh = lane >> 4;
  const int NT = K >> 6;

  // staging: per-lane inverse-swizzled global source column
  const int qs3 = ((lane & 7) ^ ((lane >> 3) & 7)) * 8;
  const uint16_t* gA_ = A  + (size_t)((bm << 8) + (w << 5) + (lane >> 3)) * K + qs3;
  const uint16_t* gB_ = Bt + (size_t)((bn << 7) + (w << 4) + (lane >> 3)) * K + qs3;
  uint16_t* lA_ = LA + (w << 11);    // wave-uniform LDS bases
  uint16_t* lB_ = LB + (w << 10);

  // fragment-read swizzled offsets (elements)
  const int sw0 = ((lh       ^ (l15 & 7)) << 3);   // kc=0
  const int sw1 = (((4 | lh) ^ (l15 & 7)) << 3);   // kc=1
  const int aoff = (((wm << 6) + l15) << 6);       // rows wm*64 + mi*16 + l15
  const int boff = (((wn << 5) + l15) << 6);       // rows wn*32 + ... + l15
  const int bno[4] = {0, 1024, 4096, 5120};        // (ni&1)*16*64 + (ni>>1)*64*64

  f32x4 acc[4][4];
#pragma unroll
  for (int i=0;i<4;i++)
#pragma unroll
    for (int j=0;j<4;j++) acc[i][j] = f32x4{0.f,0.f,0.f,0.f};

  auto STAGE_A = [&](int tt, int s, int i){
    GLD16(gA_ + (size_t)tt*64 + (size_t)(i*8)*K, lA_ + s*16384 + i*512);
  };
  auto STAGE_B = [&](int tt, int s, int i){
    GLD16(gB_ + (size_t)tt*64 + (size_t)(i*8)*K, lB_ + s*8192 + i*512);
  };

  // prologue: stage tiles 0,1; wait tile 0 (6 of 12 outstanding = tile 1)
#pragma unroll
  for (int i=0;i<4;i++) STAGE_A(0, 0, i);
#pragma unroll
  for (int i=0;i<2;i++) STAGE_B(0, 0, i);
#pragma unroll
  for (int i=0;i<4;i++) STAGE_A(1, 1, i);
#pragma unroll
  for (int i=0;i<2;i++) STAGE_B(1, 1, i);
  asm volatile("s_waitcnt vmcnt(6)" ::: "memory");
  __builtin_amdgcn_s_barrier();

  int sl = 0, sl2 = 2;
  for (int t = 0; t < NT; ++t){
    const bool pf = (t + 2 < NT);
    const uint16_t* la = LA + sl*16384;
    const uint16_t* lb = LB + sl*8192;

    // all fragment reads for this tile (both kc) - async, lgkm-counted
    bf16x8 af0[4], bf0[4], af1[4], bf1[4];
#pragma unroll
    for (int mi=0;mi<4;mi++) af0[mi] = *(const bf16x8*)(la + aoff + mi*1024 + sw0);
#pragma unroll
    for (int ni=0;ni<4;ni++) bf0[ni] = *(const bf16x8*)(lb + boff + bno[ni] + sw0);
#pragma unroll
    for (int mi=0;mi<4;mi++) af1[mi] = *(const bf16x8*)(la + aoff + mi*1024 + sw1);
#pragma unroll
    for (int ni=0;ni<4;ni++) bf1[ni] = *(const bf16x8*)(lb + boff + bno[ni] + sw1);
    // next-next tile staging (slot disjoint from all live readers)
    if (pf){
      STAGE_A(t+2, sl2, 0); STAGE_A(t+2, sl2, 1);
      STAGE_A(t+2, sl2, 2); STAGE_A(t+2, sl2, 3);
      STAGE_B(t+2, sl2, 0); STAGE_B(t+2, sl2, 1);
    }
    // 32 MFMAs; compiler inserts fine-grained lgkmcnt before first uses
    __builtin_amdgcn_s_setprio(1);
#pragma unroll
    for (int mi=0;mi<4;mi++)
#pragma unroll
      for (int ni=0;ni<4;ni++)
        acc[mi][ni] = __builtin_amdgcn_mfma_f32_16x16x32_bf16(af0[mi], bf0[ni], acc[mi][ni], 0, 0, 0);
#pragma unroll
    for (int mi=0;mi<4;mi++)
#pragma unroll
      for (int ni=0;ni<4;ni++)
        acc[mi][ni] = __builtin_amdgcn_mfma_f32_16x16x32_bf16(af1[mi], bf1[ni], acc[mi][ni], 0, 0, 0);
    __builtin_amdgcn_s_setprio(0);

    // ---- tile boundary: counted vmcnt + single barrier ----
    if (t < NT-2)       { asm volatile("s_waitcnt vmcnt(6)" ::: "memory"); }
    else if (t == NT-2) { asm volatile("s_waitcnt vmcnt(0)" ::: "memory"); }
    if (t < NT-1) __builtin_amdgcn_s_barrier();
    sl  = (sl  == 2) ? 0 : sl  + 1;
    sl2 = (sl2 == 2) ? 0 : sl2 + 1;
  }

  // ---- epilogue ----
  const int cm = (bm << 8) + (wm << 6);
  const int cn = (bn << 7);
  int dc[4];
#pragma unroll
  for (int ni=0;ni<4;ni++) dc[ni] = (wn<<5) + ((ni>>1)<<6) + ((ni&1)<<4) + l15;
  float bs[4];
#pragma unroll
  for (int ni=0;ni<4;ni++) bs[ni] = bias[cn + dc[ni]];

  if (MODE == 0){
#pragma unroll
    for (int mi=0;mi<4;mi++)
#pragma unroll
      for (int r=0;r<4;r++){
        int rowg = cm + mi*16 + lh*4 + r;       // C/D: col=lane&15, row=(lane>>4)*4+r
#pragma unroll
        for (int ni=0;ni<4;ni++)
          ((float*)Cv)[(size_t)rowg * ldc + cn + dc[ni]] = acc[mi][ni][r] + bs[ni];
      }
  } else {
    const int part = bn >> 4;                   // 0=q, 1=k, 2=v
    if (part == 2){
      // bias + direct transposed store: vt[((b*16+h)*128 + d)*2048 + t]
      uint16_t* vtp = (uint16_t*)Cv2;
      const int h  = bn & 15;
      const int bb = cm >> 11;                  // batch index (256-row blocks don't cross)
      const int t0 = (cm & (L_-1)) + lh*4;
#pragma unroll
      for (int mi=0;mi<4;mi++){
#pragma unroll
        for (int ni=0;ni<4;ni++){
          ushort4v pk;
#pragma unroll
          for (int r=0;r<4;r++) pk[r] = f2bf(acc[mi][ni][r] + bs[ni]);
          *(ushort4v*)(vtp + ((size_t)((bb*16 + h)*128 + dc[ni]))*L_ + t0 + mi*16) = pk;
        }
      }
    } else {
      // fused bias + RMSNorm + RoPE (fp32 domain) -> qk[ldc=4096]
      uint16_t* Cb = (uint16_t*)Cv;
      const float* scp = part ? ks : qs;
      float scv[4];
#pragma unroll
      for (int ni=0;ni<4;ni++) scv[ni] = scp[dc[ni]];
      float ssum[4][4];
#pragma unroll
      for (int mi=0;mi<4;mi++)
#pragma unroll
        for (int r=0;r<4;r++){
          float s = 0.f;
#pragma unroll
          for (int ni=0;ni<4;ni++){
            float v = acc[mi][ni][r] + bs[ni];
            acc[mi][ni][r] = v;
            s += v*v;
          }
          s += __shfl_xor(s, 1); s += __shfl_xor(s, 2);
          s += __shfl_xor(s, 4); s += __shfl_xor(s, 8);
          ssum[mi][r] = s;                       // own 64-col half sum
        }
      if (l15 == 0){
#pragma unroll
        for (int mi=0;mi<4;mi++)
#pragma unroll
          for (int r=0;r<4;r++) sums[wm][wn][mi*16 + lh*4 + r] = ssum[mi][r];
      }
      __syncthreads();
      const int dd0 = (wn<<5) + l15, dd1 = dd0 + 16;
#pragma unroll
      for (int mi=0;mi<4;mi++){
#pragma unroll
        for (int r=0;r<4;r++){
          int rid = mi*16 + lh*4 + r;
          float tot = ssum[mi][r] + sums[wm][wn^1][rid];
          float iv = rsqrtf(tot * 0.0078125f + 1e-6f);
          int rowg = cm + rid;
          int t = rowg & (L_-1);
          float y0 = acc[mi][0][r] * iv * scv[0];
          float y1 = acc[mi][1][r] * iv * scv[1];
          float y2 = acc[mi][2][r] * iv * scv[2];
          float y3 = acc[mi][3][r] * iv * scv[3];
          float c0 = ct[t*64 + dd0], s0 = st[t*64 + dd0];
          float c1 = ct[t*64 + dd1], s1 = st[t*64 + dd1];
          size_t rb_ = (size_t)rowg * ldc + cn;
          Cb[rb_ + dc[0]] = f2bf(y0*c0 - y2*s0);
          Cb[rb_ + dc[1]] = f2bf(y1*c1 - y3*s1);
          Cb[rb_ + dc[2]] = f2bf(y0*s0 + y2*c0);
          Cb[rb_ + dc[3]] = f2bf(y1*s1 + y3*c1);
        }
      }
    }
  }
}

// ---------------- flash attention (causal, balanced pairs, R16) ----------
// grid (bh=32, qp=16): bh = blockIdx.x -> all 16 qp-blocks of a bh land on
// XCD bh%8 (32%8==0): 4 bh x 1MB K/V = 4MB = one XCD L2; 64 blocks/XCD =
// exactly 2-block/CU capacity. Block handles q-tiles {qp, 31-qp}: 33 K-tile
// iters, uniform. KVBLK=64, 4 waves x 16 q-rows. Q in regs; K,V
// reg-prefetched -> padded LDS. Swapped QK^T (mfma(K,Q)) lane-local softmax;
// P as 4x ds_write_b64; T5 setprio; T13 defer-max.
__global__ __launch_bounds__(256) void flash_attn(
    const uint16_t* __restrict__ qk, const uint16_t* __restrict__ vt,
    uint16_t* __restrict__ ao)
{
  const int bh = blockIdx.x;          // 0..31  (XCD-local per bh)
  const int qp = blockIdx.y;          // 0..15
  const int b = bh >> 4, h = bh & 15;
  const int tid = threadIdx.x;
  const int lane = tid & 63, w = tid >> 6;
  const int l15 = lane & 15, lh = lane >> 4;

  __shared__ uint16_t Ks[64][136];
  __shared__ uint16_t Vs[128][72];
  __shared__ uint16_t Ps[4][16][72];

  const float SCL = 0.12751744f;      // (1/sqrt(128)) * log2(e)

  for (int sel = 0; sel < 2; sel++){
    const int qb = sel ? (31 - qp) : qp;

    const size_t qrow = (size_t)b * L_ + qb*64 + w*16 + l15;
    const uint16_t* qp_ = qk + qrow * QKW + h * HD;
    bf16x8 qf[4];
#pragma unroll
    for (int c = 0; c < 4; c++) qf[c] = *(const bf16x8*)(qp_ + c*32 + lh*8);

    float m_s = -3.0e38f, l_s = 0.f;   // per-lane scalars for q = l15
    f32x4 oacc[8];
#pragma unroll
    for (int nt = 0; nt < 8; nt++) oacc[nt] = f32x4{0.f,0.f,0.f,0.f};

    const int ntile = qb + 1;
    ushort8 rk[4], rv[4];

#pragma unroll
    for (int i = 0; i < 4; i++){
      int g = i*256 + tid, row = g >> 4, c = g & 15;
      rk[i] = *(const ushort8*)(qk + ((size_t)b*L_ + row)*QKW + DM + h*HD + c*8);
    }
#pragma unroll
    for (int i = 0; i < 4; i++){
      int g = i*256 + tid, d = g >> 3, c = g & 7;
      rv[i] = *(const ushort8*)(vt + ((size_t)bh*HD + d)*L_ + c*8);
    }

    for (int kt = 0; kt < ntile; kt++){
      __syncthreads();                  // prior tile's LDS reads complete
#pragma unroll
      for (int i = 0; i < 4; i++){ int g = i*256+tid; *(ushort8*)(&Ks[g>>4][(g&15)*8]) = rk[i]; }
#pragma unroll
      for (int i = 0; i < 4; i++){ int g = i*256+tid; *(ushort8*)(&Vs[g>>3][(g&7)*8]) = rv[i]; }
      __syncthreads();

      if (kt + 1 < ntile){
        const int k2 = (kt + 1) * 64;
#pragma unroll
        for (int i = 0; i < 4; i++){
          int g = i*256 + tid, row = g >> 4, c = g & 15;
          rk[i] = *(const ushort8*)(qk + ((size_t)b*L_ + k2 + row)*QKW + DM + h*HD + c*8);
        }
#pragma unroll
        for (int i = 0; i < 4; i++){
          int g = i*256 + tid, d = g >> 3, c = g & 7;
          rv[i] = *(const ushort8*)(vt + ((size_t)bh*HD + d)*L_ + k2 + c*8);
        }
      }

      // ---- S^T = K Q^T : s[nt][r] = S[k = nt*16+lh*4+r][q = l15] ----
      f32x4 s[4];
#pragma unroll
      for (int nt = 0; nt < 4; nt++) s[nt] = f32x4{0.f,0.f,0.f,0.f};
      __builtin_amdgcn_s_setprio(1);
#pragma unroll
      for (int c = 0; c < 4; c++){
#pragma unroll
        for (int nt = 0; nt < 4; nt++){
          bf16x8 kf = *(const bf16x8*)(&Ks[nt*16 + l15][c*32 + lh*8]);
          s[nt] = __builtin_amdgcn_mfma_f32_16x16x32_bf16(kf, qf[c], s[nt], 0, 0, 0);
        }
      }
      __builtin_amdgcn_s_setprio(0);

      // ---- scale + causal mask (log2 domain) ----
      const bool diag = (kt == qb);
      const int qg = w*16 + l15;            // q within block
      const int kb = lh*4;                  // k base within each 16-k tile
#pragma unroll
      for (int nt = 0; nt < 4; nt++){
#pragma unroll
        for (int r = 0; r < 4; r++){
          float v = s[nt][r] * SCL;
          if (diag && (nt*16 + kb + r > qg)) v = -1.0e30f;
          s[nt][r] = v;
        }
      }
      // ---- lane-local max over 16 k + 2 cross-lh shuffles ----
      float pm = s[0][0];
#pragma unroll
      for (int nt = 0; nt < 4; nt++)
#pragma unroll
        for (int r = 0; r < 4; r++) pm = fmaxf(pm, s[nt][r]);
      pm = fmaxf(pm, __shfl_xor(pm, 16));
      pm = fmaxf(pm, __shfl_xor(pm, 32));
      // ---- T13 defer-max ----
      if (!__all(pm - m_s <= 8.0f)){
        float mn = fmaxf(m_s, pm);
        float alpha = exp2f(m_s - mn);
        m_s = mn; l_s *= alpha;
        float ar[4];
#pragma unroll
        for (int r = 0; r < 4; r++) ar[r] = __shfl(alpha, lh*4 + r);
#pragma unroll
        for (int nt = 0; nt < 8; nt++)
#pragma unroll
          for (int r = 0; r < 4; r++) oacc[nt][r] *= ar[r];
      }
      // ---- P = exp2(S - m), pack 4 consecutive k, store b64; sum ----
      float rs = 0.f;
#pragma unroll
      for (int nt = 0; nt < 4; nt++){
        float p0 = exp2f(s[nt][0] - m_s);
        float p1 = exp2f(s[nt][1] - m_s);
        float p2 = exp2f(s[nt][2] - m_s);
        float p3 = exp2f(s[nt][3] - m_s);
        rs += (p0 + p1) + (p2 + p3);
        uint2 pk;
        pk.x = (uint32_t)f2bf(p0) | ((uint32_t)f2bf(p1) << 16);
        pk.y = (uint32_t)f2bf(p2) | ((uint32_t)f2bf(p3) << 16);
        *(uint2*)(&Ps[w][l15][nt*16 + kb]) = pk;
      }
      rs += __shfl_xor(rs, 16);
      rs += __shfl_xor(rs, 32);
      l_s += rs;

      asm volatile("s_waitcnt lgkmcnt(0)" ::: "memory");   // Ps writes visible (wave-private)
      // ---- O += P V : A=P[16q][64k] (LDS), B=V[64k][128d] (LDS) ----
      __builtin_amdgcn_s_setprio(1);
#pragma unroll
      for (int kc = 0; kc < 2; kc++){
        bf16x8 pf = *(const bf16x8*)(&Ps[w][l15][kc*32 + lh*8]);
#pragma unroll
        for (int nt = 0; nt < 8; nt++){
          bf16x8 vf = *(const bf16x8*)(&Vs[nt*16 + l15][kc*32 + lh*8]);
          oacc[nt] = __builtin_amdgcn_mfma_f32_16x16x32_bf16(pf, vf, oacc[nt], 0, 0, 0);
        }
      }
      __builtin_amdgcn_s_setprio(0);
    }
    // ---- epilogue: redistribute l to oacc rows, O /= l, write ----
    float invl[4];
#pragma unroll
    for (int r = 0; r < 4; r++) invl[r] = 1.f / __shfl(l_s, lh*4 + r);
#pragma unroll
    for (int nt = 0; nt < 8; nt++){
#pragma unroll
      for (int r = 0; r < 4; r++){
        float v = oacc[nt][r] * invl[r];
        size_t row = (size_t)b*L_ + qb*64 + w*16 + lh*4 + r;
        ao[row * DM + h*HD + nt*16 + l15] = f2bf(v);
      }
    }
  }
}

// ---------------------------------------------------------------------------
extern "C" void kernel_launch(void* const* d_in, const int* in_sizes, int n_in,
                              void* d_out, int out_size, void* d_ws, size_t ws_size,
                              hipStream_t stream)
{
  (void)in_sizes; (void)n_in; (void)out_size; (void)ws_size;
  const float* x       = (const float*)d_in[0];
  const float* w_qkv   = (const float*)d_in[1];
  const float* b_qkv   = (const float*)d_in[2];
  const float* q_scale = (const float*)d_in[3];
  const float* k_scale = (const float*)d_in[4];
  const float* w_out   = (const float*)d_in[5];
  const float* b_out   = (const float*)d_in[6];
  float* out = (float*)d_out;

  // workspace layout (101.7 MB), lifetime-based reuse
  char* ws = (char*)d_ws;
  uint16_t* qk    = (uint16_t*)(ws);                  // 33,554,432 B  [4096][4096]
  uint16_t* vt    = (uint16_t*)(ws + 33554432);       // 16,777,216 B  [32][128][2048]
  uint16_t* reg1  = (uint16_t*)(ws + 50331648);       // 16,777,216 B  xb -> ao
  uint16_t* wqkvT = (uint16_t*)(ws + 67108864);       // 25,165,824 B
  uint16_t* woutT = (uint16_t*)(ws + 92274688);       //  8,388,608 B
  float*    ct    = (float*)(ws + 100663296);         //    524,288 B
  float*    st    = ct + 131072;                      //    524,288 B

  uint16_t* xb = reg1;   // x bf16 [4096][2048]  (dead after gemm_qkv)
  uint16_t* ao = reg1;   // attn out bf16 [4096][2048]

  prep        <<<8704, 256, 0, stream>>>(w_qkv, wqkvT, w_out, woutT, x, xb, ct, st);
  gemm8p<1>   <<<768, 512, 0, stream>>>(xb, wqkvT, b_qkv, qk, vt,
                                        4096, 6144, 2048, 48, 4096,
                                        q_scale, k_scale, ct, st);
  flash_attn  <<<dim3(32, 16), 256, 0, stream>>>(qk, vt, ao);
  gemm8p<0>   <<<256, 512, 0, stream>>>(ao, woutT, b_out, out, nullptr,
                                        4096, 2048, 2048, 16, 2048,
                                        nullptr, nullptr, nullptr, nullptr);
}